// Round 1
// 352.158 us; speedup vs baseline: 1.0219x; 1.0219x over previous
//
#include <hip/hip_runtime.h>
#include <hip/hip_bf16.h>

typedef unsigned short u16;
typedef unsigned int   u32;
typedef unsigned long long u64;

#define SEQ 1024
#define EMB 1024
#define NH  16
#define DKH 64

// 0.125 (1/sqrt(64)) * log2(e): folded into Wq/bq so attn uses exp2 directly
#define QSCALE 0.18033688f
#define SCLAMP 43.3f

typedef __attribute__((ext_vector_type(8))) short short8;
typedef __attribute__((ext_vector_type(4))) float floatx4;

__device__ __forceinline__ float b2f(u16 u) {
  return __uint_as_float(((u32)u) << 16);
}
__device__ __forceinline__ u16 f2b(float f) {
  u32 u = __float_as_uint(f);
  u32 r = u + 0x7fffu + ((u >> 16) & 1u);   // RNE
  return (u16)(r >> 16);
}

// async global->LDS, 16 B per lane; LDS dst = wave-uniform base + lane*16
__device__ __forceinline__ void glds16(const u16* g, u16* l) {
  __builtin_amdgcn_global_load_lds(
      (const __attribute__((address_space(1))) u32*)g,
      (__attribute__((address_space(3))) u32*)l, 16, 0, 0);
}

// ---------- probe the two 8M-element buffers ----------
// flags[0]=xIsB, flags[1]=x storage (1=bf16,0=fp32), flags[2]=mask bytes (1) vs int32 (0)
__global__ __launch_bounds__(256) void probe_inputs(const u32* __restrict__ A,
                                                    const u32* __restrict__ B,
                                                    int* __restrict__ flags) {
  __shared__ int mA, mB, mBig, xB16;
  if (threadIdx.x == 0) { mA = 0; mB = 0; mBig = 0; xB16 = 0; }
  __syncthreads();
  int la = 0, lb = 0;
  for (int i = threadIdx.x; i < 4096; i += 256) {
    if ((A[i] & 0xFEFEFEFEu) == 0) la++;
    if ((B[i] & 0xFEFEFEFEu) == 0) lb++;
  }
  atomicAdd(&mA, la); atomicAdd(&mB, lb);
  __syncthreads();
  const int xIsB = (mA > mB) ? 1 : 0;
  const u32* X = xIsB ? B : A;
  const u32* M = xIsB ? A : B;
  int big = 0, cnt = 0;
  for (int i = threadIdx.x; i < 4096; i += 256)
    if (M[i] > 1u) big = 1;
  for (int i = threadIdx.x; i < 2048; i += 256) {
    u16 v = (u16)(X[i] & 0xffffu);
    int e = (v >> 7) & 0xFF;
    if (e >= 110 && e <= 135) cnt++;
  }
  if (big) atomicOr(&mBig, 1);
  atomicAdd(&xB16, cnt);
  __syncthreads();
  if (threadIdx.x == 0) {
    flags[0] = xIsB;
    flags[1] = (xB16 > 1500) ? 1 : 0;
    flags[2] = mBig;
  }
}

// ---------- convert x to bf16 once (or copy if already bf16) ----------
__global__ __launch_bounds__(256) void convert_x(const void* __restrict__ bigA,
                                                 const void* __restrict__ bigB,
                                                 const int* __restrict__ flags,
                                                 u16* __restrict__ out) {
  const void* x = flags[0] ? bigB : bigA;
  int i = (blockIdx.x * 256 + threadIdx.x) * 4;
  if (flags[1]) {
    *(ushort4*)(out + i) = *(const ushort4*)((const u16*)x + i);
  } else {
    float4 v = *(const float4*)((const float*)x + i);
    ushort4 o;
    o.x = f2b(v.x); o.y = f2b(v.y); o.z = f2b(v.z); o.w = f2b(v.w);
    *(ushort4*)(out + i) = o;
  }
}

// ---------- pack mask to 1 bit/element via ballot (coalesced) ----------
__global__ __launch_bounds__(256) void build_maskbits(const void* __restrict__ bigA,
                                                      const void* __restrict__ bigB,
                                                      const int* __restrict__ flags,
                                                      u32* __restrict__ out) {
  const void* mask = flags[0] ? bigA : bigB;
  const int mbyte = flags[2];
  const int t = threadIdx.x;
  const int lane = t & 63, w = t >> 6;
  const u64 base0 = (u64)blockIdx.x * 8192;
#pragma unroll 4
  for (int k = 0; k < 32; k++) {
    u64 idx = base0 + k * 256 + t;
    int v;
    if (mbyte) v = ((const unsigned char*)mask)[idx] != 0;
    else       v = ((const u32*)mask)[idx] != 0;
    u64 b = __ballot(v);
    if (lane == 0) {
      u64 wbase = (base0 + k * 256 + w * 64) >> 5;
      out[wbase]     = (u32)b;
      out[wbase + 1] = (u32)(b >> 32);
    }
  }
}

// ---------- transpose(+convert) all 4 weights in one dispatch ----------
__global__ __launch_bounds__(256) void transpose_convert_w4(
    const void* __restrict__ w0, const void* __restrict__ w1,
    const void* __restrict__ w2, const void* __restrict__ w3,
    u16* __restrict__ outQKV, u16* __restrict__ outO,
    const int* __restrict__ flags) {
  __shared__ float tile[32][33];
  const int z = blockIdx.z;
  const void* in = (z == 0) ? w0 : (z == 1) ? w1 : (z == 2) ? w2 : w3;
  u16* out = (z < 3) ? (outQKV + (u64)z * EMB * EMB) : outO;
  const float scale = (z == 0) ? QSCALE : 1.0f;
  const int amode = flags[1];
  const int tx = threadIdx.x & 31;
  const int ty = threadIdx.x >> 5;
  const int bx = blockIdx.x * 32, by = blockIdx.y * 32;
  if (amode) {
    const u16* inb = (const u16*)in;
#pragma unroll
    for (int r = ty; r < 32; r += 8)
      tile[r][tx] = b2f(inb[(u64)(by + r) * EMB + bx + tx]);
  } else {
    const float* inf = (const float*)in;
#pragma unroll
    for (int r = ty; r < 32; r += 8)
      tile[r][tx] = inf[(u64)(by + r) * EMB + bx + tx];
  }
  __syncthreads();
#pragma unroll
  for (int r = ty; r < 32; r += 8)
    out[(u64)(bx + r) * EMB + by + tx] = f2b(tile[tx][r] * scale);
}

// ---------- stage 4 bias vectors into fp32 ws (bq pre-scaled) ----------
__global__ __launch_bounds__(256) void convert_biases(const void* b0, const void* b1,
                                                      const void* b2, const void* b3,
                                                      float* __restrict__ out,
                                                      const int* __restrict__ flags) {
  const void* ptrs[4] = {b0, b1, b2, b3};
  const void* p = ptrs[blockIdx.x];
  const float scale = (blockIdx.x == 0) ? QSCALE : 1.0f;
  const int amode = flags[1];
  for (int i = threadIdx.x; i < 1024; i += 256) {
    float v = amode ? b2f(((const u16*)p)[i]) : ((const float*)p)[i];
    out[blockIdx.x * 1024 + i] = v * scale;
  }
}

// ---------- per-head V transpose: [s][d] -> [d][s] ----------
#define VTP 65
__global__ __launch_bounds__(256) void transpose_v(const u16* __restrict__ in,
                                                   u16* __restrict__ out) {
  __shared__ u16 tile[64 * VTP];
  const int t = threadIdx.x;
  const int s0 = blockIdx.x * 64;
  const u64 off = (u64)blockIdx.y * SEQ * DKH;
  const int row = t >> 2, c0 = (t & 3) * 16;
  const u16* ip = in + off + (u64)(s0 + row) * DKH + c0;
  *(uint4*)(&tile[row * VTP + c0])     = *(const uint4*)(ip);
  *(uint4*)(&tile[row * VTP + c0 + 8]) = *(const uint4*)(ip + 8);
  __syncthreads();
  const int d = t >> 2;
  u16 buf[16];
#pragma unroll
  for (int j = 0; j < 16; j++) buf[j] = tile[(c0 + j) * VTP + d];
  u16* op = out + off + (u64)d * SEQ + s0 + c0;
  *(uint4*)(op)     = *(uint4*)(&buf[0]);
  *(uint4*)(op + 8) = *(uint4*)(&buf[8]);
}

// ---------- fused QKV GEMM with global_load_lds staging (bf16 X) ----------
// [Q|K|V] = xb @ WtQKV^T + bias; output heads layout per 1024-col section.
__global__ __launch_bounds__(256) void gemm_qkv(
    const u16* __restrict__ X, const u16* __restrict__ Wt,
    const float* __restrict__ bias,
    u16* __restrict__ Qg, u16* __restrict__ Kg, u16* __restrict__ Vh,
    int row0) {
  __shared__ u16 As[128 * 32];
  __shared__ u16 Bs[128 * 32];
  const int t = threadIdx.x;
  const int lane = t & 63;
  const int w4 = t >> 6;
  const int wm = w4 >> 1, wn = w4 & 1;
  const int bM = blockIdx.x * 128, bN = blockIdx.y * 128;
  const int l15 = lane & 15, l4 = lane >> 4;

  floatx4 acc[4][4];
#pragma unroll
  for (int i = 0; i < 4; i++)
#pragma unroll
    for (int j = 0; j < 4; j++)
      acc[i][j] = (floatx4){0.f, 0.f, 0.f, 0.f};

  // staging geometry: wave w covers rows [w*32, w*32+32) via 2 issues of 16 rows
  const int rb = w4 * 32 + (lane >> 2);
  const int cb = (lane & 3) * 8;
  const u16* Ap = X + (u64)(row0 + bM + rb) * EMB + cb;
  const u16* Bp = Wt + (u64)(bN + rb) * EMB + cb;
  u16* AsW = &As[(w4 * 32) * 32];
  u16* BsW = &Bs[(w4 * 32) * 32];

  for (int k0 = 0; k0 < EMB; k0 += 32) {
    __syncthreads();
    glds16(Ap + k0, AsW);
    glds16(Ap + 16 * EMB + k0, AsW + 512);
    glds16(Bp + k0, BsW);
    glds16(Bp + 16 * EMB + k0, BsW + 512);
    __syncthreads();
    short8 af[4], bfr[4];
#pragma unroll
    for (int i = 0; i < 4; i++) {
      af[i]  = *(const short8*)(&As[(wm * 64 + i * 16 + l15) * 32 + l4 * 8]);
      bfr[i] = *(const short8*)(&Bs[(wn * 64 + i * 16 + l15) * 32 + l4 * 8]);
    }
#pragma unroll
    for (int i = 0; i < 4; i++)
#pragma unroll
      for (int j = 0; j < 4; j++)
        acc[i][j] = __builtin_amdgcn_mfma_f32_16x16x32_bf16(af[i], bfr[j], acc[i][j], 0, 0, 0);
  }

  const int sec = bN >> 10;                 // 0=Q,1=K,2=V (block-uniform)
  u16* outp = (sec == 0) ? Qg : (sec == 1) ? Kg : Vh;
#pragma unroll
  for (int j = 0; j < 4; j++) {
    int col = bN + wn * 64 + j * 16 + l15;
    float bv = bias[col];
    int colh = col & 1023;
    int h = colh >> 6, d = colh & 63;
#pragma unroll
    for (int i = 0; i < 4; i++) {
#pragma unroll
      for (int r = 0; r < 4; r++) {
        int row = bM + wm * 64 + i * 16 + l4 * 4 + r;
        float v = acc[i][j][r] + bv;
        int n = row >> 10, s = row & 1023;
        outp[((u64)((n * NH + h) * SEQ + s)) * DKH + d] = f2b(v);
      }
    }
  }
}

// ---------- O GEMM with global_load_lds: out_fp32 = ctx @ WtO^T + bo ----------
__global__ __launch_bounds__(256) void gemm_out(
    const u16* __restrict__ X, const u16* __restrict__ Wt,
    const float* __restrict__ bias, float* __restrict__ out) {
  __shared__ u16 As[128 * 32];
  __shared__ u16 Bs[128 * 32];
  const int t = threadIdx.x;
  const int lane = t & 63;
  const int w4 = t >> 6;
  const int wm = w4 >> 1, wn = w4 & 1;
  const int bM = blockIdx.x * 128, bN = blockIdx.y * 128;
  const int l15 = lane & 15, l4 = lane >> 4;

  floatx4 acc[4][4];
#pragma unroll
  for (int i = 0; i < 4; i++)
#pragma unroll
    for (int j = 0; j < 4; j++)
      acc[i][j] = (floatx4){0.f, 0.f, 0.f, 0.f};

  const int rb = w4 * 32 + (lane >> 2);
  const int cb = (lane & 3) * 8;
  const u16* Ap = X + (u64)(bM + rb) * EMB + cb;
  const u16* Bp = Wt + (u64)(bN + rb) * EMB + cb;
  u16* AsW = &As[(w4 * 32) * 32];
  u16* BsW = &Bs[(w4 * 32) * 32];

  for (int k0 = 0; k0 < EMB; k0 += 32) {
    __syncthreads();
    glds16(Ap + k0, AsW);
    glds16(Ap + 16 * EMB + k0, AsW + 512);
    glds16(Bp + k0, BsW);
    glds16(Bp + 16 * EMB + k0, BsW + 512);
    __syncthreads();
    short8 af[4], bfr[4];
#pragma unroll
    for (int i = 0; i < 4; i++) {
      af[i]  = *(const short8*)(&As[(wm * 64 + i * 16 + l15) * 32 + l4 * 8]);
      bfr[i] = *(const short8*)(&Bs[(wn * 64 + i * 16 + l15) * 32 + l4 * 8]);
    }
#pragma unroll
    for (int i = 0; i < 4; i++)
#pragma unroll
      for (int j = 0; j < 4; j++)
        acc[i][j] = __builtin_amdgcn_mfma_f32_16x16x32_bf16(af[i], bfr[j], acc[i][j], 0, 0, 0);
  }

#pragma unroll
  for (int j = 0; j < 4; j++) {
    int col = bN + wn * 64 + j * 16 + l15;
    float bv = bias[col];
#pragma unroll
    for (int i = 0; i < 4; i++) {
#pragma unroll
      for (int r = 0; r < 4; r++) {
        int row = bM + wm * 64 + i * 16 + l4 * 4 + r;
        out[(u64)row * EMB + col] = acc[i][j][r] + bv;
      }
    }
  }
}

// ---------- MFMA flash attention, v2 ----------
// Changes vs v1:
//  * [64][64] LDS tiles with XOR swizzle (chunk ^= (row&7)) instead of ATS=72 pad
//    -> conflict-free ds_read_b128 / ds_write (was 1.15e7 conflict cycles)
//  * K/V staged via global_load_lds (linear LDS dst, inverse-swizzled per-lane
//    global src, m173 pattern), double-buffered: loads for tile t+1 issued
//    before compute of tile t, ONE barrier per tile (T3-lite 2-phase)
//  * s_setprio(1) around MFMA clusters (T5)
__global__ __launch_bounds__(256) void attn_mfma(
    const u16* __restrict__ Q, const u16* __restrict__ K,
    const u16* __restrict__ Vt, const u32* __restrict__ maskbits,
    int b0, u16* __restrict__ ctx) {
  __shared__ __align__(16) u16 Ks[2][64 * 64];   // [s_local][d], swizzled
  __shared__ __align__(16) u16 Vs[2][64 * 64];   // [d][s_local], swizzled
  __shared__ __align__(16) u16 Ps[64 * 64];      // [q_local][s_local], swizzled

  const int t = threadIdx.x;
  const int lane = t & 63, w = t >> 6;
  const int l15 = lane & 15, l4 = lane >> 4;
  const int bid = blockIdx.x;
  const int h = bid & 15;
  const int qt = (bid >> 4) & 15;
  const int n = bid >> 8;
  const int nh = n * NH + h;
  const int q0 = qt * 64;
  const u64 hoff = (u64)nh * SEQ * DKH;

  // swizzle: element (row, col) lives at col ^ ((row&7)<<3). For all fragment
  // accesses row&7 == l15&7, so the two 16B-chunk offsets are:
  const int r7 = l15 & 7;
  const int cA = (l4 ^ r7) << 3;        // actual cols l4*8   .. +8
  const int cB = (l4 ^ r7 ^ 4) << 3;    // actual cols 32+l4*8.. +8

  // staging: wave w, issue q in {0,1}: tile row rt=(w*2+q)*8+(lane>>3),
  // 16B chunk (lane&7). LDS dst linear (base+lane*16); global src gets the
  // inverse swizzle: chunk ^= rt&7 == lane>>3.
  const int rt0 = w * 16 + (lane >> 3);
  const int rt1 = rt0 + 8;
  const int chk = ((lane & 7) ^ (lane >> 3)) << 3;   // elements
  const u16* Kp0 = K + hoff + (u64)rt0 * DKH + chk;
  const u16* Kp1 = K + hoff + (u64)rt1 * DKH + chk;
  const u16* Vp0 = Vt + hoff + (u64)rt0 * SEQ + chk;
  const u16* Vp1 = Vt + hoff + (u64)rt1 * SEQ + chk;
  const int ldsO0 = w * 1024;           // elements: wave-uniform
  const int ldsO1 = ldsO0 + 512;

  short8 qf0, qf1;
  {
    const u16* qp = Q + hoff + (u64)(q0 + w * 16 + l15) * DKH + l4 * 8;
    qf0 = *(const short8*)(qp);
    qf1 = *(const short8*)(qp + 32);
  }

  floatx4 o[4];
#pragma unroll
  for (int j = 0; j < 4; j++) o[j] = (floatx4){0.f, 0.f, 0.f, 0.f};
  float lsum = 0.f;

  const u64 mrow = ((u64)((b0 + n) * SEQ + q0 + w * 16 + l15)) * 32;
  const int pq = w * 16 + l15;

  // prologue: stage tile 0 into buffer 0
  glds16(Kp0, &Ks[0][ldsO0]);
  glds16(Kp1, &Ks[0][ldsO1]);
  glds16(Vp0, &Vs[0][ldsO0]);
  glds16(Vp1, &Vs[0][ldsO1]);
  __syncthreads();

  int cur = 0;
  for (int kc = 0; kc < SEQ; kc += 64) {
    // issue next tile's loads first (hidden under this tile's compute)
    if (kc + 64 < SEQ) {
      const int nb = cur ^ 1;
      const int ko = (kc + 64) * DKH;
      const int vo = kc + 64;
      glds16(Kp0 + ko, &Ks[nb][ldsO0]);
      glds16(Kp1 + ko, &Ks[nb][ldsO1]);
      glds16(Vp0 + vo, &Vs[nb][ldsO0]);
      glds16(Vp1 + vo, &Vs[nb][ldsO1]);
    }
    const u64 mbits = *(const u64*)(maskbits + mrow + (kc >> 5));
    const u16* Kc = &Ks[cur][0];
    const u16* Vc = &Vs[cur][0];

    __builtin_amdgcn_s_setprio(1);
#pragma unroll
    for (int j = 0; j < 4; j++) {
      floatx4 s = (floatx4){0.f, 0.f, 0.f, 0.f};
      const int rb = (j * 16 + l15) * 64;
      short8 kb0 = *(const short8*)(&Kc[rb + cA]);
      short8 kb1 = *(const short8*)(&Kc[rb + cB]);
      s = __builtin_amdgcn_mfma_f32_16x16x32_bf16(kb0, qf0, s, 0, 0, 0);
      s = __builtin_amdgcn_mfma_f32_16x16x32_bf16(kb1, qf1, s, 0, 0, 0);

      const u32 mj = (u32)(mbits >> (j * 16 + l4 * 4)) & 0xFu;
      float p0 = (mj & 1u) ? 0.f : exp2f(fminf(s[0], SCLAMP));
      float p1 = (mj & 2u) ? 0.f : exp2f(fminf(s[1], SCLAMP));
      float p2 = (mj & 4u) ? 0.f : exp2f(fminf(s[2], SCLAMP));
      float p3 = (mj & 8u) ? 0.f : exp2f(fminf(s[3], SCLAMP));
      lsum += (p0 + p1) + (p2 + p3);
      __hip_bfloat162 pk01 = __float22bfloat162_rn(make_float2(p0, p1));
      __hip_bfloat162 pk23 = __float22bfloat162_rn(make_float2(p2, p3));
      uint2 pk;
      pk.x = *(u32*)&pk01;
      pk.y = *(u32*)&pk23;
      const int pcol = ((j * 16) + (l4 * 4)) ^ (r7 << 3);
      *(uint2*)(&Ps[pq * 64 + pcol]) = pk;
    }

    short8 pa0 = *(const short8*)(&Ps[pq * 64 + cA]);
    short8 pa1 = *(const short8*)(&Ps[pq * 64 + cB]);
#pragma unroll
    for (int j = 0; j < 4; j++) {
      const int rb = (j * 16 + l15) * 64;
      short8 vb0 = *(const short8*)(&Vc[rb + cA]);
      short8 vb1 = *(const short8*)(&Vc[rb + cB]);
      o[j] = __builtin_amdgcn_mfma_f32_16x16x32_bf16(pa0, vb0, o[j], 0, 0, 0);
      o[j] = __builtin_amdgcn_mfma_f32_16x16x32_bf16(pa1, vb1, o[j], 0, 0, 0);
    }
    __builtin_amdgcn_s_setprio(0);

    __syncthreads();   // drains vmcnt (next tile staged) + all reads of cur
    cur ^= 1;
  }

  lsum += __shfl_xor(lsum, 16, 64);
  lsum += __shfl_xor(lsum, 32, 64);
  float inv = 1.0f / fmaxf(lsum, 1e-30f);

#pragma unroll
  for (int r = 0; r < 4; r++) {
    float invr = __shfl(inv, l4 * 4 + r, 64);
    int q = q0 + w * 16 + l4 * 4 + r;
    u64 base = ((u64)(n * SEQ + q)) * EMB + h * DKH + l15;
#pragma unroll
    for (int j = 0; j < 4; j++)
      ctx[base + j * 16] = f2b(o[j][r] * invr);
  }
}

extern "C" void kernel_launch(void* const* d_in, const int* in_sizes, int n_in,
                              void* d_out, int out_size, void* d_ws, size_t ws_size,
                              hipStream_t stream) {
  // Identify buffers by size class; x vs mask (same size) resolved on-device.
  int bigI[2] = {0, 1}, wI[4] = {2, 4, 6, 8}, bI[4] = {3, 5, 7, 9};
  int nb = 0, nw = 0, nbi = 0;
  for (int i = 0; i < n_in; i++) {
    if (in_sizes[i] == 8388608) { if (nb < 2) bigI[nb++] = i; }
    else if (in_sizes[i] == 1048576) { if (nw < 4) wI[nw++] = i; }
    else if (in_sizes[i] == 1024) { if (nbi < 4) bI[nbi++] = i; }
  }
  int oq = 0, ok = 1, ov = 2, oo = 3;
  if (nb == 2 && bigI[0] == 4 && bigI[1] == 9) { oq = 2; ok = 0; ov = 3; oo = 1; }

  const void* bigA = d_in[bigI[0]];
  const void* bigB = d_in[bigI[1]];
  const void* Wq = d_in[wI[oq]];
  const void* Wk = d_in[wI[ok]];
  const void* Wv = d_in[wI[ov]];
  const void* Wo = d_in[wI[oo]];
  const void* bq = d_in[bI[oq]];
  const void* bk = d_in[bI[ok]];
  const void* bv = d_in[bI[ov]];
  const void* bo = d_in[bI[oo]];

  char* ws = (char*)d_ws;
  // [0,6MB) WtQKV; [6,8MB) WtO; 8MB: biases (16KB); +16KB flags; +64KB maskbits (1MB);
  // [10,26MB) xb (bf16 x); group region at 26MB: Qg/Kg/Vh/Vt, 2MB*G each; ctx aliases Vh.
  u16* WtQKV = (u16*)ws;
  u16* WtO   = (u16*)(ws + (6ull << 20));
  float* biasf = (float*)(ws + (8ull << 20));
  int* flags = (int*)(ws + (8ull << 20) + 16384);
  u32* maskbits = (u32*)(ws + (8ull << 20) + 65536);
  u16* xb = (u16*)(ws + (10ull << 20));
  char* grp = ws + (26ull << 20);

  int G = 1;
  for (int g = 8; g >= 1; g >>= 1) {
    if (ws_size >= (26ull << 20) + (u64)g * (8ull << 20)) { G = g; break; }
  }
  const u64 gsz = (u64)G * (2ull << 20);
  u16* Qg = (u16*)grp;
  u16* Kg = (u16*)(grp + gsz);
  u16* Vh = (u16*)(grp + 2 * gsz);     // V heads layout; later reused as ctx
  u16* Vt = (u16*)(grp + 3 * gsz);     // V transposed [d][s]

  dim3 tb(256);

  probe_inputs<<<dim3(1), tb, 0, stream>>>((const u32*)bigA, (const u32*)bigB, flags);
  convert_x<<<dim3(8192), tb, 0, stream>>>(bigA, bigB, flags, xb);
  build_maskbits<<<dim3(1024), tb, 0, stream>>>(bigA, bigB, flags, maskbits);

  transpose_convert_w4<<<dim3(32, 32, 4), tb, 0, stream>>>(Wq, Wk, Wv, Wo, WtQKV, WtO, flags);
  convert_biases<<<dim3(4), tb, 0, stream>>>(bq, bk, bv, bo, biasf, flags);

  for (int b0 = 0; b0 < 8; b0 += G) {
    int row0 = b0 * 1024;
    gemm_qkv<<<dim3(8 * G, 24), tb, 0, stream>>>(xb, WtQKV, biasf, Qg, Kg, Vh, row0);
    transpose_v<<<dim3(16, G * 16), tb, 0, stream>>>(Vh, Vt);

    attn_mfma<<<dim3(G * 16 * 16), tb, 0, stream>>>(Qg, Kg, Vt, maskbits, b0, Vh);

    gemm_out<<<dim3(8 * G, 8), tb, 0, stream>>>(Vh, WtO, biasf + 3072,
                                                (float*)d_out + (u64)row0 * EMB);
  }
}

// Round 2
// 335.802 us; speedup vs baseline: 1.0717x; 1.0487x over previous
//
#include <hip/hip_runtime.h>
#include <hip/hip_bf16.h>

typedef unsigned short u16;
typedef unsigned int   u32;
typedef unsigned long long u64;

#define SEQ 1024
#define EMB 1024
#define NH  16
#define DKH 64

// 0.125 (1/sqrt(64)) * log2(e): folded into Wq/bq so attn uses exp2 directly
#define QSCALE 0.18033688f
#define SCLAMP 43.3f

typedef __attribute__((ext_vector_type(8))) short short8;
typedef __attribute__((ext_vector_type(4))) float floatx4;

__device__ __forceinline__ float b2f(u16 u) {
  return __uint_as_float(((u32)u) << 16);
}
__device__ __forceinline__ u16 f2b(float f) {
  u32 u = __float_as_uint(f);
  u32 r = u + 0x7fffu + ((u >> 16) & 1u);   // RNE
  return (u16)(r >> 16);
}

// async global->LDS, 16 B per lane; LDS dst = wave-uniform base + lane*16
__device__ __forceinline__ void glds16(const u16* g, u16* l) {
  __builtin_amdgcn_global_load_lds(
      (const __attribute__((address_space(1))) u32*)g,
      (__attribute__((address_space(3))) u32*)l, 16, 0, 0);
}

// ---------- probe the two 8M-element buffers ----------
// flags[0]=xIsB, flags[1]=x storage (1=bf16,0=fp32), flags[2]=mask bytes (1) vs int32 (0)
__global__ __launch_bounds__(256) void probe_inputs(const u32* __restrict__ A,
                                                    const u32* __restrict__ B,
                                                    int* __restrict__ flags) {
  __shared__ int mA, mB, mBig, xB16;
  if (threadIdx.x == 0) { mA = 0; mB = 0; mBig = 0; xB16 = 0; }
  __syncthreads();
  int la = 0, lb = 0;
  for (int i = threadIdx.x; i < 4096; i += 256) {
    if ((A[i] & 0xFEFEFEFEu) == 0) la++;
    if ((B[i] & 0xFEFEFEFEu) == 0) lb++;
  }
  atomicAdd(&mA, la); atomicAdd(&mB, lb);
  __syncthreads();
  const int xIsB = (mA > mB) ? 1 : 0;
  const u32* X = xIsB ? B : A;
  const u32* M = xIsB ? A : B;
  int big = 0, cnt = 0;
  for (int i = threadIdx.x; i < 4096; i += 256)
    if (M[i] > 1u) big = 1;
  for (int i = threadIdx.x; i < 2048; i += 256) {
    u16 v = (u16)(X[i] & 0xffffu);
    int e = (v >> 7) & 0xFF;
    if (e >= 110 && e <= 135) cnt++;
  }
  if (big) atomicOr(&mBig, 1);
  atomicAdd(&xB16, cnt);
  __syncthreads();
  if (threadIdx.x == 0) {
    flags[0] = xIsB;
    flags[1] = (xB16 > 1500) ? 1 : 0;
    flags[2] = mBig;
  }
}

// ---------- convert x to bf16 once (or copy if already bf16) ----------
__global__ __launch_bounds__(256) void convert_x(const void* __restrict__ bigA,
                                                 const void* __restrict__ bigB,
                                                 const int* __restrict__ flags,
                                                 u16* __restrict__ out) {
  const void* x = flags[0] ? bigB : bigA;
  int i = (blockIdx.x * 256 + threadIdx.x) * 4;
  if (flags[1]) {
    *(ushort4*)(out + i) = *(const ushort4*)((const u16*)x + i);
  } else {
    float4 v = *(const float4*)((const float*)x + i);
    ushort4 o;
    o.x = f2b(v.x); o.y = f2b(v.y); o.z = f2b(v.z); o.w = f2b(v.w);
    *(ushort4*)(out + i) = o;
  }
}

// ---------- pack mask to 1 bit/element via ballot (coalesced) ----------
// NOTE: stores KEEP bits (1 = attend, 0 = suppressed) so attn can use
// sign-extended-bit AND masking.
__global__ __launch_bounds__(256) void build_maskbits(const void* __restrict__ bigA,
                                                      const void* __restrict__ bigB,
                                                      const int* __restrict__ flags,
                                                      u32* __restrict__ out) {
  const void* mask = flags[0] ? bigA : bigB;
  const int mbyte = flags[2];
  const int t = threadIdx.x;
  const int lane = t & 63, w = t >> 6;
  const u64 base0 = (u64)blockIdx.x * 8192;
#pragma unroll 4
  for (int k = 0; k < 32; k++) {
    u64 idx = base0 + k * 256 + t;
    int v;
    if (mbyte) v = ((const unsigned char*)mask)[idx] == 0;
    else       v = ((const u32*)mask)[idx] == 0;
    u64 b = __ballot(v);
    if (lane == 0) {
      u64 wbase = (base0 + k * 256 + w * 64) >> 5;
      out[wbase]     = (u32)b;
      out[wbase + 1] = (u32)(b >> 32);
    }
  }
}

// ---------- transpose(+convert) all 4 weights in one dispatch ----------
__global__ __launch_bounds__(256) void transpose_convert_w4(
    const void* __restrict__ w0, const void* __restrict__ w1,
    const void* __restrict__ w2, const void* __restrict__ w3,
    u16* __restrict__ outQKV, u16* __restrict__ outO,
    const int* __restrict__ flags) {
  __shared__ float tile[32][33];
  const int z = blockIdx.z;
  const void* in = (z == 0) ? w0 : (z == 1) ? w1 : (z == 2) ? w2 : w3;
  u16* out = (z < 3) ? (outQKV + (u64)z * EMB * EMB) : outO;
  const float scale = (z == 0) ? QSCALE : 1.0f;
  const int amode = flags[1];
  const int tx = threadIdx.x & 31;
  const int ty = threadIdx.x >> 5;
  const int bx = blockIdx.x * 32, by = blockIdx.y * 32;
  if (amode) {
    const u16* inb = (const u16*)in;
#pragma unroll
    for (int r = ty; r < 32; r += 8)
      tile[r][tx] = b2f(inb[(u64)(by + r) * EMB + bx + tx]);
  } else {
    const float* inf = (const float*)in;
#pragma unroll
    for (int r = ty; r < 32; r += 8)
      tile[r][tx] = inf[(u64)(by + r) * EMB + bx + tx];
  }
  __syncthreads();
#pragma unroll
  for (int r = ty; r < 32; r += 8)
    out[(u64)(bx + r) * EMB + by + tx] = f2b(tile[tx][r] * scale);
}

// ---------- stage 4 bias vectors into fp32 ws (bq pre-scaled) ----------
__global__ __launch_bounds__(256) void convert_biases(const void* b0, const void* b1,
                                                      const void* b2, const void* b3,
                                                      float* __restrict__ out,
                                                      const int* __restrict__ flags) {
  const void* ptrs[4] = {b0, b1, b2, b3};
  const void* p = ptrs[blockIdx.x];
  const float scale = (blockIdx.x == 0) ? QSCALE : 1.0f;
  const int amode = flags[1];
  for (int i = threadIdx.x; i < 1024; i += 256) {
    float v = amode ? b2f(((const u16*)p)[i]) : ((const float*)p)[i];
    out[blockIdx.x * 1024 + i] = v * scale;
  }
}

// ---------- per-head V transpose: [s][d] -> [d][s] ----------
#define VTP 65
__global__ __launch_bounds__(256) void transpose_v(const u16* __restrict__ in,
                                                   u16* __restrict__ out) {
  __shared__ u16 tile[64 * VTP];
  const int t = threadIdx.x;
  const int s0 = blockIdx.x * 64;
  const u64 off = (u64)blockIdx.y * SEQ * DKH;
  const int row = t >> 2, c0 = (t & 3) * 16;
  const u16* ip = in + off + (u64)(s0 + row) * DKH + c0;
  *(uint4*)(&tile[row * VTP + c0])     = *(const uint4*)(ip);
  *(uint4*)(&tile[row * VTP + c0 + 8]) = *(const uint4*)(ip + 8);
  __syncthreads();
  const int d = t >> 2;
  u16 buf[16];
#pragma unroll
  for (int j = 0; j < 16; j++) buf[j] = tile[(c0 + j) * VTP + d];
  u16* op = out + off + (u64)d * SEQ + s0 + c0;
  *(uint4*)(op)     = *(uint4*)(&buf[0]);
  *(uint4*)(op + 8) = *(uint4*)(&buf[8]);
}

// ---------- fused QKV GEMM with global_load_lds staging (bf16 X) ----------
// [Q|K|V] = xb @ WtQKV^T + bias; output heads layout per 1024-col section.
__global__ __launch_bounds__(256) void gemm_qkv(
    const u16* __restrict__ X, const u16* __restrict__ Wt,
    const float* __restrict__ bias,
    u16* __restrict__ Qg, u16* __restrict__ Kg, u16* __restrict__ Vh,
    int row0) {
  __shared__ u16 As[128 * 32];
  __shared__ u16 Bs[128 * 32];
  const int t = threadIdx.x;
  const int lane = t & 63;
  const int w4 = t >> 6;
  const int wm = w4 >> 1, wn = w4 & 1;
  const int bM = blockIdx.x * 128, bN = blockIdx.y * 128;
  const int l15 = lane & 15, l4 = lane >> 4;

  floatx4 acc[4][4];
#pragma unroll
  for (int i = 0; i < 4; i++)
#pragma unroll
    for (int j = 0; j < 4; j++)
      acc[i][j] = (floatx4){0.f, 0.f, 0.f, 0.f};

  // staging geometry: wave w covers rows [w*32, w*32+32) via 2 issues of 16 rows
  const int rb = w4 * 32 + (lane >> 2);
  const int cb = (lane & 3) * 8;
  const u16* Ap = X + (u64)(row0 + bM + rb) * EMB + cb;
  const u16* Bp = Wt + (u64)(bN + rb) * EMB + cb;
  u16* AsW = &As[(w4 * 32) * 32];
  u16* BsW = &Bs[(w4 * 32) * 32];

  for (int k0 = 0; k0 < EMB; k0 += 32) {
    __syncthreads();
    glds16(Ap + k0, AsW);
    glds16(Ap + 16 * EMB + k0, AsW + 512);
    glds16(Bp + k0, BsW);
    glds16(Bp + 16 * EMB + k0, BsW + 512);
    __syncthreads();
    short8 af[4], bfr[4];
#pragma unroll
    for (int i = 0; i < 4; i++) {
      af[i]  = *(const short8*)(&As[(wm * 64 + i * 16 + l15) * 32 + l4 * 8]);
      bfr[i] = *(const short8*)(&Bs[(wn * 64 + i * 16 + l15) * 32 + l4 * 8]);
    }
#pragma unroll
    for (int i = 0; i < 4; i++)
#pragma unroll
      for (int j = 0; j < 4; j++)
        acc[i][j] = __builtin_amdgcn_mfma_f32_16x16x32_bf16(af[i], bfr[j], acc[i][j], 0, 0, 0);
  }

  const int sec = bN >> 10;                 // 0=Q,1=K,2=V (block-uniform)
  u16* outp = (sec == 0) ? Qg : (sec == 1) ? Kg : Vh;
#pragma unroll
  for (int j = 0; j < 4; j++) {
    int col = bN + wn * 64 + j * 16 + l15;
    float bv = bias[col];
    int colh = col & 1023;
    int h = colh >> 6, d = colh & 63;
#pragma unroll
    for (int i = 0; i < 4; i++) {
#pragma unroll
      for (int r = 0; r < 4; r++) {
        int row = bM + wm * 64 + i * 16 + l4 * 4 + r;
        float v = acc[i][j][r] + bv;
        int n = row >> 10, s = row & 1023;
        outp[((u64)((n * NH + h) * SEQ + s)) * DKH + d] = f2b(v);
      }
    }
  }
}

// ---------- O GEMM with global_load_lds: out_fp32 = ctx @ WtO^T + bo ----------
__global__ __launch_bounds__(256) void gemm_out(
    const u16* __restrict__ X, const u16* __restrict__ Wt,
    const float* __restrict__ bias, float* __restrict__ out) {
  __shared__ u16 As[128 * 32];
  __shared__ u16 Bs[128 * 32];
  const int t = threadIdx.x;
  const int lane = t & 63;
  const int w4 = t >> 6;
  const int wm = w4 >> 1, wn = w4 & 1;
  const int bM = blockIdx.x * 128, bN = blockIdx.y * 128;
  const int l15 = lane & 15, l4 = lane >> 4;

  floatx4 acc[4][4];
#pragma unroll
  for (int i = 0; i < 4; i++)
#pragma unroll
    for (int j = 0; j < 4; j++)
      acc[i][j] = (floatx4){0.f, 0.f, 0.f, 0.f};

  const int rb = w4 * 32 + (lane >> 2);
  const int cb = (lane & 3) * 8;
  const u16* Ap = X + (u64)(bM + rb) * EMB + cb;
  const u16* Bp = Wt + (u64)(bN + rb) * EMB + cb;
  u16* AsW = &As[(w4 * 32) * 32];
  u16* BsW = &Bs[(w4 * 32) * 32];

  for (int k0 = 0; k0 < EMB; k0 += 32) {
    __syncthreads();
    glds16(Ap + k0, AsW);
    glds16(Ap + 16 * EMB + k0, AsW + 512);
    glds16(Bp + k0, BsW);
    glds16(Bp + 16 * EMB + k0, BsW + 512);
    __syncthreads();
    short8 af[4], bfr[4];
#pragma unroll
    for (int i = 0; i < 4; i++) {
      af[i]  = *(const short8*)(&As[(wm * 64 + i * 16 + l15) * 32 + l4 * 8]);
      bfr[i] = *(const short8*)(&Bs[(wn * 64 + i * 16 + l15) * 32 + l4 * 8]);
    }
#pragma unroll
    for (int i = 0; i < 4; i++)
#pragma unroll
      for (int j = 0; j < 4; j++)
        acc[i][j] = __builtin_amdgcn_mfma_f32_16x16x32_bf16(af[i], bfr[j], acc[i][j], 0, 0, 0);
  }

#pragma unroll
  for (int j = 0; j < 4; j++) {
    int col = bN + wn * 64 + j * 16 + l15;
    float bv = bias[col];
#pragma unroll
    for (int i = 0; i < 4; i++) {
#pragma unroll
      for (int r = 0; r < 4; r++) {
        int row = bM + wm * 64 + i * 16 + l4 * 4 + r;
        out[(u64)row * EMB + col] = acc[i][j][r] + bv;
      }
    }
  }
}

// ---------- MFMA flash attention, v3 ----------
// Changes vs v2:
//  * 512-thread (8-wave) blocks, 128 q-rows sharing one K/V tile:
//    LDS 48KB -> 3 blocks/CU = 24 waves/CU (was 12), K/V staged once per
//    8 waves (4x less staging work/wave, 2x fewer K/V L2 re-reads)
//  * VALU diet: keep-bit mask via v_bfe_i32 sign-extend + AND on fp32 bits;
//    P pack via inline-asm v_cvt_pk_bf16_f32 (T12); row-sum via MFMA with
//    all-ones B fragment (osum lands in same C-layout as o -> no shuffles)
__global__ __launch_bounds__(512, 6) void attn_mfma(
    const u16* __restrict__ Q, const u16* __restrict__ K,
    const u16* __restrict__ Vt, const u32* __restrict__ maskbits,
    int b0, u16* __restrict__ ctx) {
  __shared__ __align__(16) u16 Ks[2][64 * 64];   // [s_local][d], swizzled
  __shared__ __align__(16) u16 Vs[2][64 * 64];   // [d][s_local], swizzled
  __shared__ __align__(16) u16 Ps[128 * 64];     // [q_local][s_local], swizzled

  const int t = threadIdx.x;
  const int lane = t & 63, w = t >> 6;           // w in 0..7
  const int l15 = lane & 15, l4 = lane >> 4;
  const int bid = blockIdx.x;
  const int h = bid & 15;
  const int qt = (bid >> 4) & 7;
  const int n = bid >> 7;
  const int nh = n * NH + h;
  const int q0 = qt * 128;
  const u64 hoff = (u64)nh * SEQ * DKH;

  // swizzle: element (row, col) lives at col ^ ((row&7)<<3). For all fragment
  // accesses row&7 == l15&7, so the two 16B-chunk offsets are:
  const int r7 = l15 & 7;
  const int cA = (l4 ^ r7) << 3;        // actual cols l4*8   .. +8
  const int cB = (l4 ^ r7 ^ 4) << 3;    // actual cols 32+l4*8.. +8

  // staging: wave w stages tile rows w*8 .. w*8+7 (one glds16 each for K,V).
  // LDS dst linear (base+lane*16); global src gets the inverse swizzle.
  const int rt = w * 8 + (lane >> 3);
  const int chk = ((lane & 7) ^ (lane >> 3)) << 3;   // elements
  const u16* Kp = K + hoff + (u64)rt * DKH + chk;
  const u16* Vp = Vt + hoff + (u64)rt * SEQ + chk;
  const int ldsO = w * 512;             // elements: wave-uniform

  short8 qf0, qf1;
  {
    const u16* qp = Q + hoff + (u64)(q0 + w * 16 + l15) * DKH + l4 * 8;
    qf0 = *(const short8*)(qp);
    qf1 = *(const short8*)(qp + 32);
  }

  short8 ones;
#pragma unroll
  for (int e = 0; e < 8; e++) ones[e] = (short)0x3F80;   // bf16 1.0

  floatx4 o[4];
#pragma unroll
  for (int j = 0; j < 4; j++) o[j] = (floatx4){0.f, 0.f, 0.f, 0.f};
  floatx4 osum = (floatx4){0.f, 0.f, 0.f, 0.f};

  const u64 mrow = ((u64)((b0 + n) * SEQ + q0 + w * 16 + l15)) * 32;
  const int pq = w * 16 + l15;
  const int pc0 = (l4 * 4) ^ (r7 << 3);

  // prologue: stage tile 0 into buffer 0
  glds16(Kp, &Ks[0][ldsO]);
  glds16(Vp, &Vs[0][ldsO]);
  __syncthreads();

  int cur = 0;
  for (int kc = 0; kc < SEQ; kc += 64) {
    // issue next tile's loads first (hidden under this tile's compute)
    if (kc + 64 < SEQ) {
      const int nb = cur ^ 1;
      glds16(Kp + (kc + 64) * DKH, &Ks[nb][ldsO]);
      glds16(Vp + (kc + 64), &Vs[nb][ldsO]);
    }
    const u64 mbits = *(const u64*)(maskbits + mrow + (kc >> 5));
    const u16* Kc = &Ks[cur][0];
    const u16* Vc = &Vs[cur][0];

    __builtin_amdgcn_s_setprio(1);
#pragma unroll
    for (int j = 0; j < 4; j++) {
      floatx4 s = (floatx4){0.f, 0.f, 0.f, 0.f};
      const int rb = (j * 16 + l15) * 64;
      short8 kb0 = *(const short8*)(&Kc[rb + cA]);
      short8 kb1 = *(const short8*)(&Kc[rb + cB]);
      s = __builtin_amdgcn_mfma_f32_16x16x32_bf16(kb0, qf0, s, 0, 0, 0);
      s = __builtin_amdgcn_mfma_f32_16x16x32_bf16(kb1, qf1, s, 0, 0, 0);

      // keep-bits: bit==1 -> attend. sbfe sign-extends the bit to 0 / ~0,
      // AND with the fp32 exp result zeroes suppressed entries (1 op each).
      const u32 mj = (u32)(mbits >> (j * 16 + l4 * 4));
      float p0 = __uint_as_float(
          __float_as_uint(__builtin_amdgcn_exp2f(fminf(s[0], SCLAMP))) &
          (u32)__builtin_amdgcn_sbfe(mj, 0, 1));
      float p1 = __uint_as_float(
          __float_as_uint(__builtin_amdgcn_exp2f(fminf(s[1], SCLAMP))) &
          (u32)__builtin_amdgcn_sbfe(mj, 1, 1));
      float p2 = __uint_as_float(
          __float_as_uint(__builtin_amdgcn_exp2f(fminf(s[2], SCLAMP))) &
          (u32)__builtin_amdgcn_sbfe(mj, 2, 1));
      float p3 = __uint_as_float(
          __float_as_uint(__builtin_amdgcn_exp2f(fminf(s[3], SCLAMP))) &
          (u32)__builtin_amdgcn_sbfe(mj, 3, 1));

      uint2 pk;
      asm("v_cvt_pk_bf16_f32 %0, %1, %2" : "=v"(pk.x) : "v"(p0), "v"(p1));
      asm("v_cvt_pk_bf16_f32 %0, %1, %2" : "=v"(pk.y) : "v"(p2), "v"(p3));
      *(uint2*)(&Ps[pq * 64 + ((j * 16) ^ pc0)]) = pk;
    }

    short8 pa0 = *(const short8*)(&Ps[pq * 64 + cA]);
    short8 pa1 = *(const short8*)(&Ps[pq * 64 + cB]);
#pragma unroll
    for (int j = 0; j < 4; j++) {
      const int rb = (j * 16 + l15) * 64;
      short8 vb0 = *(const short8*)(&Vc[rb + cA]);
      short8 vb1 = *(const short8*)(&Vc[rb + cB]);
      o[j] = __builtin_amdgcn_mfma_f32_16x16x32_bf16(pa0, vb0, o[j], 0, 0, 0);
      o[j] = __builtin_amdgcn_mfma_f32_16x16x32_bf16(pa1, vb1, o[j], 0, 0, 0);
    }
    // row-sum of P on the matrix pipe: C[q][*] = sum_k P[q][k]
    osum = __builtin_amdgcn_mfma_f32_16x16x32_bf16(pa0, ones, osum, 0, 0, 0);
    osum = __builtin_amdgcn_mfma_f32_16x16x32_bf16(pa1, ones, osum, 0, 0, 0);
    __builtin_amdgcn_s_setprio(0);

    __syncthreads();   // drains vmcnt (next tile staged) + all reads of cur
    cur ^= 1;
  }

  // osum[r] is the softmax denominator for exactly the rows o[j][r] holds.
#pragma unroll
  for (int r = 0; r < 4; r++) {
    float invr = 1.0f / fmaxf(osum[r], 1e-30f);
    int q = q0 + w * 16 + l4 * 4 + r;
    u64 base = ((u64)(n * SEQ + q)) * EMB + h * DKH + l15;
#pragma unroll
    for (int j = 0; j < 4; j++)
      ctx[base + j * 16] = f2b(o[j][r] * invr);
  }
}

extern "C" void kernel_launch(void* const* d_in, const int* in_sizes, int n_in,
                              void* d_out, int out_size, void* d_ws, size_t ws_size,
                              hipStream_t stream) {
  // Identify buffers by size class; x vs mask (same size) resolved on-device.
  int bigI[2] = {0, 1}, wI[4] = {2, 4, 6, 8}, bI[4] = {3, 5, 7, 9};
  int nb = 0, nw = 0, nbi = 0;
  for (int i = 0; i < n_in; i++) {
    if (in_sizes[i] == 8388608) { if (nb < 2) bigI[nb++] = i; }
    else if (in_sizes[i] == 1048576) { if (nw < 4) wI[nw++] = i; }
    else if (in_sizes[i] == 1024) { if (nbi < 4) bI[nbi++] = i; }
  }
  int oq = 0, ok = 1, ov = 2, oo = 3;
  if (nb == 2 && bigI[0] == 4 && bigI[1] == 9) { oq = 2; ok = 0; ov = 3; oo = 1; }

  const void* bigA = d_in[bigI[0]];
  const void* bigB = d_in[bigI[1]];
  const void* Wq = d_in[wI[oq]];
  const void* Wk = d_in[wI[ok]];
  const void* Wv = d_in[wI[ov]];
  const void* Wo = d_in[wI[oo]];
  const void* bq = d_in[bI[oq]];
  const void* bk = d_in[bI[ok]];
  const void* bv = d_in[bI[ov]];
  const void* bo = d_in[bI[oo]];

  char* ws = (char*)d_ws;
  // [0,6MB) WtQKV; [6,8MB) WtO; 8MB: biases (16KB); +16KB flags; +64KB maskbits (1MB);
  // [10,26MB) xb (bf16 x); group region at 26MB: Qg/Kg/Vh/Vt, 2MB*G each; ctx aliases Vh.
  u16* WtQKV = (u16*)ws;
  u16* WtO   = (u16*)(ws + (6ull << 20));
  float* biasf = (float*)(ws + (8ull << 20));
  int* flags = (int*)(ws + (8ull << 20) + 16384);
  u32* maskbits = (u32*)(ws + (8ull << 20) + 65536);
  u16* xb = (u16*)(ws + (10ull << 20));
  char* grp = ws + (26ull << 20);

  int G = 1;
  for (int g = 8; g >= 1; g >>= 1) {
    if (ws_size >= (26ull << 20) + (u64)g * (8ull << 20)) { G = g; break; }
  }
  const u64 gsz = (u64)G * (2ull << 20);
  u16* Qg = (u16*)grp;
  u16* Kg = (u16*)(grp + gsz);
  u16* Vh = (u16*)(grp + 2 * gsz);     // V heads layout; later reused as ctx
  u16* Vt = (u16*)(grp + 3 * gsz);     // V transposed [d][s]

  dim3 tb(256);

  probe_inputs<<<dim3(1), tb, 0, stream>>>((const u32*)bigA, (const u32*)bigB, flags);
  convert_x<<<dim3(8192), tb, 0, stream>>>(bigA, bigB, flags, xb);
  build_maskbits<<<dim3(1024), tb, 0, stream>>>(bigA, bigB, flags, maskbits);

  transpose_convert_w4<<<dim3(32, 32, 4), tb, 0, stream>>>(Wq, Wk, Wv, Wo, WtQKV, WtO, flags);
  convert_biases<<<dim3(4), tb, 0, stream>>>(bq, bk, bv, bo, biasf, flags);

  for (int b0 = 0; b0 < 8; b0 += G) {
    int row0 = b0 * 1024;
    gemm_qkv<<<dim3(8 * G, 24), tb, 0, stream>>>(xb, WtQKV, biasf, Qg, Kg, Vh, row0);
    transpose_v<<<dim3(16, G * 16), tb, 0, stream>>>(Vh, Vt);

    attn_mfma<<<dim3(G * 16 * 8), dim3(512), 0, stream>>>(Qg, Kg, Vt, maskbits, b0, Vh);

    gemm_out<<<dim3(8 * G, 8), tb, 0, stream>>>(Vh, WtO, biasf + 3072,
                                                (float*)d_out + (u64)row0 * EMB);
  }
}

// Round 3
// 322.037 us; speedup vs baseline: 1.1175x; 1.0427x over previous
//
#include <hip/hip_runtime.h>
#include <hip/hip_bf16.h>

typedef unsigned short u16;
typedef unsigned int   u32;
typedef unsigned long long u64;

#define SEQ 1024
#define EMB 1024
#define NH  16
#define DKH 64

// 0.125 (1/sqrt(64)) * log2(e): folded into Wq/bq so attn uses exp2 directly
#define QSCALE 0.18033688f
#define SCLAMP 43.3f

typedef __attribute__((ext_vector_type(8))) short short8;
typedef __attribute__((ext_vector_type(4))) float floatx4;

__device__ __forceinline__ float b2f(u16 u) {
  return __uint_as_float(((u32)u) << 16);
}
__device__ __forceinline__ u16 f2b(float f) {
  u32 u = __float_as_uint(f);
  u32 r = u + 0x7fffu + ((u >> 16) & 1u);   // RNE
  return (u16)(r >> 16);
}

// async global->LDS, 16 B per lane; LDS dst = wave-uniform base + lane*16
__device__ __forceinline__ void glds16(const u16* g, u16* l) {
  __builtin_amdgcn_global_load_lds(
      (const __attribute__((address_space(1))) u32*)g,
      (__attribute__((address_space(3))) u32*)l, 16, 0, 0);
}

// ---------- probe the two 8M-element buffers ----------
// flags[0]=xIsB, flags[1]=x storage (1=bf16,0=fp32), flags[2]=mask bytes (1) vs int32 (0)
__global__ __launch_bounds__(256) void probe_inputs(const u32* __restrict__ A,
                                                    const u32* __restrict__ B,
                                                    int* __restrict__ flags) {
  __shared__ int mA, mB, mBig, xB16;
  if (threadIdx.x == 0) { mA = 0; mB = 0; mBig = 0; xB16 = 0; }
  __syncthreads();
  int la = 0, lb = 0;
  for (int i = threadIdx.x; i < 4096; i += 256) {
    if ((A[i] & 0xFEFEFEFEu) == 0) la++;
    if ((B[i] & 0xFEFEFEFEu) == 0) lb++;
  }
  atomicAdd(&mA, la); atomicAdd(&mB, lb);
  __syncthreads();
  const int xIsB = (mA > mB) ? 1 : 0;
  const u32* X = xIsB ? B : A;
  const u32* M = xIsB ? A : B;
  int big = 0, cnt = 0;
  for (int i = threadIdx.x; i < 4096; i += 256)
    if (M[i] > 1u) big = 1;
  for (int i = threadIdx.x; i < 2048; i += 256) {
    u16 v = (u16)(X[i] & 0xffffu);
    int e = (v >> 7) & 0xFF;
    if (e >= 110 && e <= 135) cnt++;
  }
  if (big) atomicOr(&mBig, 1);
  atomicAdd(&xB16, cnt);
  __syncthreads();
  if (threadIdx.x == 0) {
    flags[0] = xIsB;
    flags[1] = (xB16 > 1500) ? 1 : 0;
    flags[2] = mBig;
  }
}

// ---------- convert x to bf16 once (or copy if already bf16) ----------
__global__ __launch_bounds__(256) void convert_x(const void* __restrict__ bigA,
                                                 const void* __restrict__ bigB,
                                                 const int* __restrict__ flags,
                                                 u16* __restrict__ out) {
  const void* x = flags[0] ? bigB : bigA;
  int i = (blockIdx.x * 256 + threadIdx.x) * 4;
  if (flags[1]) {
    *(ushort4*)(out + i) = *(const ushort4*)((const u16*)x + i);
  } else {
    float4 v = *(const float4*)((const float*)x + i);
    ushort4 o;
    o.x = f2b(v.x); o.y = f2b(v.y); o.z = f2b(v.z); o.w = f2b(v.w);
    *(ushort4*)(out + i) = o;
  }
}

// ---------- pack mask to 1 bit/element via ballot (coalesced) ----------
// NOTE: stores KEEP bits (1 = attend, 0 = suppressed) so attn can use
// sign-extended-bit AND masking.
__global__ __launch_bounds__(256) void build_maskbits(const void* __restrict__ bigA,
                                                      const void* __restrict__ bigB,
                                                      const int* __restrict__ flags,
                                                      u32* __restrict__ out) {
  const void* mask = flags[0] ? bigA : bigB;
  const int mbyte = flags[2];
  const int t = threadIdx.x;
  const int lane = t & 63, w = t >> 6;
  const u64 base0 = (u64)blockIdx.x * 8192;
#pragma unroll 4
  for (int k = 0; k < 32; k++) {
    u64 idx = base0 + k * 256 + t;
    int v;
    if (mbyte) v = ((const unsigned char*)mask)[idx] == 0;
    else       v = ((const u32*)mask)[idx] == 0;
    u64 b = __ballot(v);
    if (lane == 0) {
      u64 wbase = (base0 + k * 256 + w * 64) >> 5;
      out[wbase]     = (u32)b;
      out[wbase + 1] = (u32)(b >> 32);
    }
  }
}

// ---------- transpose(+convert) all 4 weights in one dispatch ----------
__global__ __launch_bounds__(256) void transpose_convert_w4(
    const void* __restrict__ w0, const void* __restrict__ w1,
    const void* __restrict__ w2, const void* __restrict__ w3,
    u16* __restrict__ outQKV, u16* __restrict__ outO,
    const int* __restrict__ flags) {
  __shared__ float tile[32][33];
  const int z = blockIdx.z;
  const void* in = (z == 0) ? w0 : (z == 1) ? w1 : (z == 2) ? w2 : w3;
  u16* out = (z < 3) ? (outQKV + (u64)z * EMB * EMB) : outO;
  const float scale = (z == 0) ? QSCALE : 1.0f;
  const int amode = flags[1];
  const int tx = threadIdx.x & 31;
  const int ty = threadIdx.x >> 5;
  const int bx = blockIdx.x * 32, by = blockIdx.y * 32;
  if (amode) {
    const u16* inb = (const u16*)in;
#pragma unroll
    for (int r = ty; r < 32; r += 8)
      tile[r][tx] = b2f(inb[(u64)(by + r) * EMB + bx + tx]);
  } else {
    const float* inf = (const float*)in;
#pragma unroll
    for (int r = ty; r < 32; r += 8)
      tile[r][tx] = inf[(u64)(by + r) * EMB + bx + tx];
  }
  __syncthreads();
#pragma unroll
  for (int r = ty; r < 32; r += 8)
    out[(u64)(bx + r) * EMB + by + tx] = f2b(tile[tx][r] * scale);
}

// ---------- stage 4 bias vectors into fp32 ws (bq pre-scaled) ----------
__global__ __launch_bounds__(256) void convert_biases(const void* b0, const void* b1,
                                                      const void* b2, const void* b3,
                                                      float* __restrict__ out,
                                                      const int* __restrict__ flags) {
  const void* ptrs[4] = {b0, b1, b2, b3};
  const void* p = ptrs[blockIdx.x];
  const float scale = (blockIdx.x == 0) ? QSCALE : 1.0f;
  const int amode = flags[1];
  for (int i = threadIdx.x; i < 1024; i += 256) {
    float v = amode ? b2f(((const u16*)p)[i]) : ((const float*)p)[i];
    out[blockIdx.x * 1024 + i] = v * scale;
  }
}

// ---------- per-head V transpose: [s][d] -> [d][s] ----------
#define VTP 65
__global__ __launch_bounds__(256) void transpose_v(const u16* __restrict__ in,
                                                   u16* __restrict__ out) {
  __shared__ u16 tile[64 * VTP];
  const int t = threadIdx.x;
  const int s0 = blockIdx.x * 64;
  const u64 off = (u64)blockIdx.y * SEQ * DKH;
  const int row = t >> 2, c0 = (t & 3) * 16;
  const u16* ip = in + off + (u64)(s0 + row) * DKH + c0;
  *(uint4*)(&tile[row * VTP + c0])     = *(const uint4*)(ip);
  *(uint4*)(&tile[row * VTP + c0 + 8]) = *(const uint4*)(ip + 8);
  __syncthreads();
  const int d = t >> 2;
  u16 buf[16];
#pragma unroll
  for (int j = 0; j < 16; j++) buf[j] = tile[(c0 + j) * VTP + d];
  u16* op = out + off + (u64)d * SEQ + s0 + c0;
  *(uint4*)(op)     = *(uint4*)(&buf[0]);
  *(uint4*)(op + 8) = *(uint4*)(&buf[8]);
}

// ============================================================================
// GEMM v2: 256x128 tile, BK=64, 8 waves (512 thr), double-buffered LDS with
// counted vmcnt(6) + raw s_barrier (T3+T4), setprio around MFMA (T5),
// XOR-swizzled LDS via inverse-swizzled global_load_lds source (T2/m173).
// Per wave: 64x64 output = acc[4][4]; per K-tile: 32 MFMA in 2 phases.
// LDS: 2 x (256+128) x 64 x 2B = 96 KB -> 1 block/CU, pipeline hides latency.
// ============================================================================

// epilogue mode 0: QKV head-scatter u16; mode 1: fp32 linear
template <int OUTMODE>
__device__ __forceinline__ void gemm_core(
    const u16* __restrict__ X, const u16* __restrict__ Wt,
    const float* __restrict__ bias,
    u16* __restrict__ Qg, u16* __restrict__ Kg, u16* __restrict__ Vh,
    float* __restrict__ outf, int row0) {
  __shared__ __align__(16) u16 lds[2][(256 + 128) * 64];
  const int t = threadIdx.x;
  const int lane = t & 63;
  const int w = t >> 6;                 // 0..7
  const int wr = w >> 1, wc = w & 1;    // wave tile: rows wr*64, cols wc*64
  const int l15 = lane & 15, l4 = lane >> 4;
  const int bM = blockIdx.x * 256, bN = blockIdx.y * 128;
  const int r7 = l15 & 7;
  const int cA = (l4 ^ r7) << 3;        // swizzled chunk for k-half 0
  const int cB = (l4 ^ r7 ^ 4) << 3;    // swizzled chunk for k-half 1

  floatx4 acc[4][4];
#pragma unroll
  for (int i = 0; i < 4; i++)
#pragma unroll
    for (int j = 0; j < 4; j++)
      acc[i][j] = (floatx4){0.f, 0.f, 0.f, 0.f};

  // staging: round covers 64 rows; wave w rows w*8+(lane>>3); chunk lane&7,
  // inverse-swizzled at the global source (LDS dst stays linear).
  const int srow = w * 8 + (lane >> 3);
  const int schk = ((lane & 7) ^ (lane >> 3)) << 3;
  const u16* Ap = X + (u64)(row0 + bM + srow) * EMB + schk;
  const u16* Bp = Wt + (u64)(bN + srow) * EMB + schk;
  u16* Ad0 = &lds[0][w * 512];
  u16* Bd0 = &lds[0][16384 + w * 512];
  u16* Ad1 = &lds[1][w * 512];
  u16* Bd1 = &lds[1][16384 + w * 512];

  auto stage = [&](u16* Ad, u16* Bd, int k0) {
    glds16(Ap + k0, Ad);
    glds16(Ap + k0 + 64 * EMB, Ad + 4096);
    glds16(Ap + k0 + 128 * EMB, Ad + 8192);
    glds16(Ap + k0 + 192 * EMB, Ad + 12288);
    glds16(Bp + k0, Bd);
    glds16(Bp + k0 + 64 * EMB, Bd + 4096);
  };

  auto compute = [&](const u16* __restrict__ Ab, const u16* __restrict__ Bb) {
    short8 bf[4][2];
#pragma unroll
    for (int n = 0; n < 4; n++) {
      const int gr = (wc * 64 + n * 16 + l15) * 64;
      bf[n][0] = *(const short8*)(&Bb[gr + cA]);
      bf[n][1] = *(const short8*)(&Bb[gr + cB]);
    }
#pragma unroll
    for (int mh = 0; mh < 2; mh++) {
      short8 af[2][2];
#pragma unroll
      for (int m = 0; m < 2; m++) {
        const int fr = (wr * 64 + mh * 32 + m * 16 + l15) * 64;
        af[m][0] = *(const short8*)(&Ab[fr + cA]);
        af[m][1] = *(const short8*)(&Ab[fr + cB]);
      }
      __builtin_amdgcn_s_setprio(1);
#pragma unroll
      for (int m = 0; m < 2; m++)
#pragma unroll
        for (int n = 0; n < 4; n++) {
          acc[mh * 2 + m][n] = __builtin_amdgcn_mfma_f32_16x16x32_bf16(
              af[m][0], bf[n][0], acc[mh * 2 + m][n], 0, 0, 0);
          acc[mh * 2 + m][n] = __builtin_amdgcn_mfma_f32_16x16x32_bf16(
              af[m][1], bf[n][1], acc[mh * 2 + m][n], 0, 0, 0);
        }
      __builtin_amdgcn_s_setprio(0);
    }
  };

  stage(Ad0, Bd0, 0);
  // 16 K-tiles, 2 per unrolled step; counted vmcnt keeps next tile in flight
  for (int k0 = 0; k0 < EMB; k0 += 128) {
    // tile at k0 in buf0; prefetch k0+64 into buf1
    stage(Ad1, Bd1, k0 + 64);
    asm volatile("s_waitcnt vmcnt(6)" ::: "memory");
    asm volatile("s_barrier" ::: "memory");
    compute(&lds[0][0], &lds[0][16384]);
    asm volatile("s_barrier" ::: "memory");
    // tile at k0+64 in buf1; prefetch k0+128 into buf0
    if (k0 + 128 < EMB) {
      stage(Ad0, Bd0, k0 + 128);
      asm volatile("s_waitcnt vmcnt(6)" ::: "memory");
    } else {
      asm volatile("s_waitcnt vmcnt(0)" ::: "memory");
    }
    asm volatile("s_barrier" ::: "memory");
    compute(&lds[1][0], &lds[1][16384]);
    asm volatile("s_barrier" ::: "memory");
  }

  if (OUTMODE == 0) {
    const int sec = bN >> 10;               // 0=Q,1=K,2=V (block-uniform)
    u16* outp = (sec == 0) ? Qg : (sec == 1) ? Kg : Vh;
#pragma unroll
    for (int n = 0; n < 4; n++) {
      int col = bN + wc * 64 + n * 16 + l15;
      float bv = bias[col];
      int colh = col & 1023;
      int h = colh >> 6, d = colh & 63;
#pragma unroll
      for (int mt = 0; mt < 4; mt++) {
#pragma unroll
        for (int r = 0; r < 4; r++) {
          int row = bM + wr * 64 + mt * 16 + l4 * 4 + r;
          float v = acc[mt][n][r] + bv;
          int nb = row >> 10, s = row & 1023;
          outp[((u64)((nb * NH + h) * SEQ + s)) * DKH + d] = f2b(v);
        }
      }
    }
  } else {
#pragma unroll
    for (int n = 0; n < 4; n++) {
      int col = bN + wc * 64 + n * 16 + l15;
      float bv = bias[col];
#pragma unroll
      for (int mt = 0; mt < 4; mt++) {
#pragma unroll
        for (int r = 0; r < 4; r++) {
          int row = bM + wr * 64 + mt * 16 + l4 * 4 + r;
          outf[(u64)row * EMB + col] = acc[mt][n][r] + bv;
        }
      }
    }
  }
}

__global__ __launch_bounds__(512, 2) void gemm_qkv(
    const u16* __restrict__ X, const u16* __restrict__ Wt,
    const float* __restrict__ bias,
    u16* __restrict__ Qg, u16* __restrict__ Kg, u16* __restrict__ Vh,
    int row0) {
  gemm_core<0>(X, Wt, bias, Qg, Kg, Vh, nullptr, row0);
}

__global__ __launch_bounds__(512, 2) void gemm_out(
    const u16* __restrict__ X, const u16* __restrict__ Wt,
    const float* __restrict__ bias, float* __restrict__ out) {
  gemm_core<1>(X, Wt, bias, nullptr, nullptr, nullptr, out, 0);
}

// ---------- MFMA flash attention (unchanged from round 2) ----------
__global__ __launch_bounds__(512, 6) void attn_mfma(
    const u16* __restrict__ Q, const u16* __restrict__ K,
    const u16* __restrict__ Vt, const u32* __restrict__ maskbits,
    int b0, u16* __restrict__ ctx) {
  __shared__ __align__(16) u16 Ks[2][64 * 64];   // [s_local][d], swizzled
  __shared__ __align__(16) u16 Vs[2][64 * 64];   // [d][s_local], swizzled
  __shared__ __align__(16) u16 Ps[128 * 64];     // [q_local][s_local], swizzled

  const int t = threadIdx.x;
  const int lane = t & 63, w = t >> 6;           // w in 0..7
  const int l15 = lane & 15, l4 = lane >> 4;
  const int bid = blockIdx.x;
  const int h = bid & 15;
  const int qt = (bid >> 4) & 7;
  const int n = bid >> 7;
  const int nh = n * NH + h;
  const int q0 = qt * 128;
  const u64 hoff = (u64)nh * SEQ * DKH;

  const int r7 = l15 & 7;
  const int cA = (l4 ^ r7) << 3;
  const int cB = (l4 ^ r7 ^ 4) << 3;

  const int rt = w * 8 + (lane >> 3);
  const int chk = ((lane & 7) ^ (lane >> 3)) << 3;
  const u16* Kp = K + hoff + (u64)rt * DKH + chk;
  const u16* Vp = Vt + hoff + (u64)rt * SEQ + chk;
  const int ldsO = w * 512;

  short8 qf0, qf1;
  {
    const u16* qp = Q + hoff + (u64)(q0 + w * 16 + l15) * DKH + l4 * 8;
    qf0 = *(const short8*)(qp);
    qf1 = *(const short8*)(qp + 32);
  }

  short8 ones;
#pragma unroll
  for (int e = 0; e < 8; e++) ones[e] = (short)0x3F80;   // bf16 1.0

  floatx4 o[4];
#pragma unroll
  for (int j = 0; j < 4; j++) o[j] = (floatx4){0.f, 0.f, 0.f, 0.f};
  floatx4 osum = (floatx4){0.f, 0.f, 0.f, 0.f};

  const u64 mrow = ((u64)((b0 + n) * SEQ + q0 + w * 16 + l15)) * 32;
  const int pq = w * 16 + l15;
  const int pc0 = (l4 * 4) ^ (r7 << 3);

  glds16(Kp, &Ks[0][ldsO]);
  glds16(Vp, &Vs[0][ldsO]);
  __syncthreads();

  int cur = 0;
  for (int kc = 0; kc < SEQ; kc += 64) {
    if (kc + 64 < SEQ) {
      const int nb = cur ^ 1;
      glds16(Kp + (kc + 64) * DKH, &Ks[nb][ldsO]);
      glds16(Vp + (kc + 64), &Vs[nb][ldsO]);
    }
    const u64 mbits = *(const u64*)(maskbits + mrow + (kc >> 5));
    const u16* Kc = &Ks[cur][0];
    const u16* Vc = &Vs[cur][0];

    __builtin_amdgcn_s_setprio(1);
#pragma unroll
    for (int j = 0; j < 4; j++) {
      floatx4 s = (floatx4){0.f, 0.f, 0.f, 0.f};
      const int rb = (j * 16 + l15) * 64;
      short8 kb0 = *(const short8*)(&Kc[rb + cA]);
      short8 kb1 = *(const short8*)(&Kc[rb + cB]);
      s = __builtin_amdgcn_mfma_f32_16x16x32_bf16(kb0, qf0, s, 0, 0, 0);
      s = __builtin_amdgcn_mfma_f32_16x16x32_bf16(kb1, qf1, s, 0, 0, 0);

      const u32 mj = (u32)(mbits >> (j * 16 + l4 * 4));
      float p0 = __uint_as_float(
          __float_as_uint(__builtin_amdgcn_exp2f(fminf(s[0], SCLAMP))) &
          (u32)__builtin_amdgcn_sbfe(mj, 0, 1));
      float p1 = __uint_as_float(
          __float_as_uint(__builtin_amdgcn_exp2f(fminf(s[1], SCLAMP))) &
          (u32)__builtin_amdgcn_sbfe(mj, 1, 1));
      float p2 = __uint_as_float(
          __float_as_uint(__builtin_amdgcn_exp2f(fminf(s[2], SCLAMP))) &
          (u32)__builtin_amdgcn_sbfe(mj, 2, 1));
      float p3 = __uint_as_float(
          __float_as_uint(__builtin_amdgcn_exp2f(fminf(s[3], SCLAMP))) &
          (u32)__builtin_amdgcn_sbfe(mj, 3, 1));

      uint2 pk;
      asm("v_cvt_pk_bf16_f32 %0, %1, %2" : "=v"(pk.x) : "v"(p0), "v"(p1));
      asm("v_cvt_pk_bf16_f32 %0, %1, %2" : "=v"(pk.y) : "v"(p2), "v"(p3));
      *(uint2*)(&Ps[pq * 64 + ((j * 16) ^ pc0)]) = pk;
    }

    short8 pa0 = *(const short8*)(&Ps[pq * 64 + cA]);
    short8 pa1 = *(const short8*)(&Ps[pq * 64 + cB]);
#pragma unroll
    for (int j = 0; j < 4; j++) {
      const int rb = (j * 16 + l15) * 64;
      short8 vb0 = *(const short8*)(&Vc[rb + cA]);
      short8 vb1 = *(const short8*)(&Vc[rb + cB]);
      o[j] = __builtin_amdgcn_mfma_f32_16x16x32_bf16(pa0, vb0, o[j], 0, 0, 0);
      o[j] = __builtin_amdgcn_mfma_f32_16x16x32_bf16(pa1, vb1, o[j], 0, 0, 0);
    }
    osum = __builtin_amdgcn_mfma_f32_16x16x32_bf16(pa0, ones, osum, 0, 0, 0);
    osum = __builtin_amdgcn_mfma_f32_16x16x32_bf16(pa1, ones, osum, 0, 0, 0);
    __builtin_amdgcn_s_setprio(0);

    __syncthreads();
    cur ^= 1;
  }

#pragma unroll
  for (int r = 0; r < 4; r++) {
    float invr = 1.0f / fmaxf(osum[r], 1e-30f);
    int q = q0 + w * 16 + l4 * 4 + r;
    u64 base = ((u64)(n * SEQ + q)) * EMB + h * DKH + l15;
#pragma unroll
    for (int j = 0; j < 4; j++)
      ctx[base + j * 16] = f2b(o[j][r] * invr);
  }
}

extern "C" void kernel_launch(void* const* d_in, const int* in_sizes, int n_in,
                              void* d_out, int out_size, void* d_ws, size_t ws_size,
                              hipStream_t stream) {
  // Identify buffers by size class; x vs mask (same size) resolved on-device.
  int bigI[2] = {0, 1}, wI[4] = {2, 4, 6, 8}, bI[4] = {3, 5, 7, 9};
  int nb = 0, nw = 0, nbi = 0;
  for (int i = 0; i < n_in; i++) {
    if (in_sizes[i] == 8388608) { if (nb < 2) bigI[nb++] = i; }
    else if (in_sizes[i] == 1048576) { if (nw < 4) wI[nw++] = i; }
    else if (in_sizes[i] == 1024) { if (nbi < 4) bI[nbi++] = i; }
  }
  int oq = 0, ok = 1, ov = 2, oo = 3;
  if (nb == 2 && bigI[0] == 4 && bigI[1] == 9) { oq = 2; ok = 0; ov = 3; oo = 1; }

  const void* bigA = d_in[bigI[0]];
  const void* bigB = d_in[bigI[1]];
  const void* Wq = d_in[wI[oq]];
  const void* Wk = d_in[wI[ok]];
  const void* Wv = d_in[wI[ov]];
  const void* Wo = d_in[wI[oo]];
  const void* bq = d_in[bI[oq]];
  const void* bk = d_in[bI[ok]];
  const void* bv = d_in[bI[ov]];
  const void* bo = d_in[bI[oo]];

  char* ws = (char*)d_ws;
  // [0,6MB) WtQKV; [6,8MB) WtO; 8MB: biases (16KB); +16KB flags; +64KB maskbits (1MB);
  // [10,26MB) xb (bf16 x); group region at 26MB: Qg/Kg/Vh/Vt, 2MB*G each; ctx aliases Vh.
  u16* WtQKV = (u16*)ws;
  u16* WtO   = (u16*)(ws + (6ull << 20));
  float* biasf = (float*)(ws + (8ull << 20));
  int* flags = (int*)(ws + (8ull << 20) + 16384);
  u32* maskbits = (u32*)(ws + (8ull << 20) + 65536);
  u16* xb = (u16*)(ws + (10ull << 20));
  char* grp = ws + (26ull << 20);

  int G = 1;
  for (int g = 8; g >= 1; g >>= 1) {
    if (ws_size >= (26ull << 20) + (u64)g * (8ull << 20)) { G = g; break; }
  }
  const u64 gsz = (u64)G * (2ull << 20);
  u16* Qg = (u16*)grp;
  u16* Kg = (u16*)(grp + gsz);
  u16* Vh = (u16*)(grp + 2 * gsz);     // V heads layout; later reused as ctx
  u16* Vt = (u16*)(grp + 3 * gsz);     // V transposed [d][s]

  dim3 tb(256);

  probe_inputs<<<dim3(1), tb, 0, stream>>>((const u32*)bigA, (const u32*)bigB, flags);
  convert_x<<<dim3(8192), tb, 0, stream>>>(bigA, bigB, flags, xb);
  build_maskbits<<<dim3(1024), tb, 0, stream>>>(bigA, bigB, flags, maskbits);

  transpose_convert_w4<<<dim3(32, 32, 4), tb, 0, stream>>>(Wq, Wk, Wv, Wo, WtQKV, WtO, flags);
  convert_biases<<<dim3(4), tb, 0, stream>>>(bq, bk, bv, bo, biasf, flags);

  for (int b0 = 0; b0 < 8; b0 += G) {
    int row0 = b0 * 1024;
    gemm_qkv<<<dim3(4 * G, 24), dim3(512), 0, stream>>>(xb, WtQKV, biasf, Qg, Kg, Vh, row0);
    transpose_v<<<dim3(16, G * 16), tb, 0, stream>>>(Vh, Vt);

    attn_mfma<<<dim3(G * 16 * 8), dim3(512), 0, stream>>>(Qg, Kg, Vt, maskbits, b0, Vh);

    gemm_out<<<dim3(4 * G, 8), dim3(512), 0, stream>>>(Vh, WtO, biasf + 3072,
                                                       (float*)d_out + (u64)row0 * EMB);
  }
}